// Round 11
// baseline (167.878 us; speedup 1.0000x reference)
//
#include <hip/hip_runtime.h>
#include <hip/hip_bf16.h>
#include <math.h>

#define B_  16
#define N_  16
#define T_  48
#define C_  512
#define H_  8
#define HD_ 64
#define L_  768
#define BL_ 12288

typedef __attribute__((ext_vector_type(8))) short b16x8;
typedef __attribute__((ext_vector_type(4))) float f32x4;
typedef __attribute__((ext_vector_type(2))) unsigned int u32x2;

__device__ __forceinline__ short f2b(float f) {
  __hip_bfloat16 h = __float2bfloat16(f);
  return *reinterpret_cast<short*>(&h);
}
// packed f32x2 -> bf16x2 (RNE), single VALU op
__device__ __forceinline__ unsigned cvt_pk_bf16(float a, float b) {
  unsigned d;
  asm("v_cvt_pk_bf16_f32 %0, %1, %2" : "=v"(d) : "v"(a), "v"(b));
  return d;
}
// 2^x, single transcendental VALU op (biases/scales pre-folded by log2e)
__device__ __forceinline__ float ex2(float x) {
  float d;
  asm("v_exp_f32 %0, %1" : "=v"(d) : "v"(x));
  return d;
}
// async global->LDS, 16B per lane; dest must be linear base + lane*16
__device__ __forceinline__ void gload16(const void* g, void* l) {
  __builtin_amdgcn_global_load_lds(
      (const __attribute__((address_space(1))) void*)g,
      (__attribute__((address_space(3))) void*)l, 16, 0, 0);
}

// ---------------------------------------------------------------------------
// prep: blocks [0,3072) cast x fp32->bf16; blocks [3072,4096) cast+transpose
// weights into WT[mat][n][k] (Wq pre-scaled by log2(e)/8 for exp2 softmax).
// ---------------------------------------------------------------------------
__global__ __launch_bounds__(256) void prep_kernel(
    const float* __restrict__ x,
    const float* __restrict__ Wq, const float* __restrict__ Wk,
    const float* __restrict__ Wv, const float* __restrict__ Wo,
    short* __restrict__ xb, short* __restrict__ WT)
{
  __shared__ float tile[32][33];
  int blk = blockIdx.x;
  int tid = threadIdx.x;
  if (blk < 3072) {
    int i = blk * 256 + tid;
    const float4* src = (const float4*)(x + (size_t)i * 8);
    float4 a = src[0], b = src[1];
    short tmp[8] = {f2b(a.x), f2b(a.y), f2b(a.z), f2b(a.w),
                    f2b(b.x), f2b(b.y), f2b(b.z), f2b(b.w)};
    *(b16x8*)(xb + (size_t)i * 8) = *(b16x8*)tmp;
  } else {
    int idx = blk - 3072;
    int mat = idx >> 8, rem = idx & 255;
    const float* W = (mat == 0) ? Wq : (mat == 1) ? Wk : (mat == 2) ? Wv : Wo;
    float scale = (mat == 0) ? 0.18033688f : 1.0f;   // log2(e)/8
    int k0 = (rem >> 4) * 32, n0 = (rem & 15) * 32;
    int tx = tid & 31, ty = tid >> 5;
    for (int i = ty; i < 32; i += 8) tile[i][tx] = W[(size_t)(k0 + i) * 512 + n0 + tx];
    __syncthreads();
    short* dst = WT + (size_t)mat * 262144;
    for (int i = ty; i < 32; i += 8)
      dst[(size_t)(n0 + i) * 512 + k0 + tx] = f2b(tile[tx][i] * scale);
  }
}

// ---------------------------------------------------------------------------
// QKV GEMM (R11): global_load_lds width-16 double-buffered staging.
//   q2,k2: [b][h][t][n][d]   vT2: [b][h][d][t][n]
// ---------------------------------------------------------------------------
__global__ __launch_bounds__(256) void qkv_kernel(
    const short* __restrict__ xb, const short* __restrict__ WT,
    short* __restrict__ q2, short* __restrict__ k2, short* __restrict__ vT2)
{
  __shared__ __align__(16) short smem[16384];  // 32KB: [buf][A 4096 | B 4096]
  int tid = threadIdx.x;
  int w = tid >> 6, lane = tid & 63, n16 = lane & 15, quad = lane >> 4;
  int bm = blockIdx.x, bn = blockIdx.y;
  int mat = bn >> 2;
  int ncol0 = (bn & 3) * 128;
  const short* Wt = WT + (size_t)mat * 262144;
  int bq = bm / 6;
  int rr0 = (bm % 6) * 128;

  f32x4 zero4 = {0.f, 0.f, 0.f, 0.f};
  f32x4 acc[4][4];
  #pragma unroll
  for (int mt = 0; mt < 4; ++mt)
    #pragma unroll
    for (int nt = 0; nt < 4; ++nt) acc[mt][nt] = zero4;

  const short* gA[2];
  const short* gB[2];
  #pragma unroll
  for (int i = 0; i < 2; ++i) {
    int r16 = w + 4 * i;
    int rr = rr0 + r16 * 16 + (lane >> 2);
    int pt = rr >> 4, pn = rr & 15;          // permuted row -> l = pn*48+pt
    gA[i] = xb + ((size_t)bq * 768 + pn * 48 + pt) * 512 + (lane & 3) * 8;
    gB[i] = Wt + (size_t)(ncol0 + r16 * 16 + (lane >> 2)) * 512 + (lane & 3) * 8;
  }
  int ldsoff = (w) * 512 + lane * 8;         // shorts, within a 4096-short tile

  auto stage = [&](int buf, int kt) {
    short* As = smem + buf * 8192;
    short* Bs = As + 4096;
    #pragma unroll
    for (int i = 0; i < 2; ++i) {
      gload16(gA[i] + kt * 32, As + i * 2048 + ldsoff);
      gload16(gB[i] + kt * 32, Bs + i * 2048 + ldsoff);
    }
  };

  int wm = (w >> 1) * 64, wn = (w & 1) * 64;
  stage(0, 0);
  __syncthreads();                           // vmcnt(0) drain + barrier
  int buf = 0;
  for (int kt = 0; kt < 16; ++kt) {
    if (kt < 15) stage(buf ^ 1, kt + 1);
    const short (*As)[32] = (const short(*)[32])(smem + buf * 8192);
    const short (*Bs)[32] = (const short(*)[32])(smem + buf * 8192 + 4096);
    b16x8 af[4], bf[4];
    #pragma unroll
    for (int mt = 0; mt < 4; ++mt) af[mt] = *(const b16x8*)&As[wm + mt * 16 + n16][quad * 8];
    #pragma unroll
    for (int nt = 0; nt < 4; ++nt) bf[nt] = *(const b16x8*)&Bs[wn + nt * 16 + n16][quad * 8];
    #pragma unroll
    for (int mt = 0; mt < 4; ++mt)
      #pragma unroll
      for (int nt = 0; nt < 4; ++nt)
        acc[mt][nt] = __builtin_amdgcn_mfma_f32_16x16x32_bf16(af[mt], bf[nt], acc[mt][nt], 0, 0, 0);
    __syncthreads();                         // waves done reading + next tile landed
    buf ^= 1;
  }

  // epilogue: 4 chunks of 32 tile-rows staged through LDS, vector stores out
  short (*Ls)[136] = (short(*)[136])smem;    // 32 x 136 (pad: aligned, spread banks)
  for (int c = 0; c < 4; ++c) {
    __syncthreads();
    if ((w >> 1) == (c >> 1)) {              // waves owning rows 32c..32c+31
      int mtb = (c & 1) * 2;
      #pragma unroll
      for (int mi = 0; mi < 2; ++mi) {
        #pragma unroll
        for (int nt = 0; nt < 4; ++nt)
          #pragma unroll
          for (int r = 0; r < 4; ++r)
            Ls[mi * 16 + quad * 4 + r][wn + nt * 16 + n16] = f2b(acc[mtb + mi][nt][r]);
      }
    }
    __syncthreads();
    int rrc = rr0 + c * 32;
    if (mat != 2) {
      short* dst = (mat == 0) ? q2 : k2;
      int row = tid >> 3, c0 = (tid & 7) * 16;
      int hhg = (ncol0 + c0) >> 6, d0 = (ncol0 + c0) & 63;
      short* dp = dst + ((size_t)(bq * 8 + hhg) * 768 + rrc + row) * 64 + d0;
      *(b16x8*)dp       = *(b16x8*)&Ls[row][c0];
      *(b16x8*)(dp + 8) = *(b16x8*)&Ls[row][c0 + 8];
    } else {
      int cp = tid & 63, r8 = (tid >> 6) * 8;
      int c0 = 2 * cp;
      int hhg = (ncol0 + c0) >> 6, d0 = (ncol0 + c0) & 63;
      short t0[8], t1[8];
      #pragma unroll
      for (int j = 0; j < 8; ++j) { t0[j] = Ls[r8 + j][c0]; t1[j] = Ls[r8 + j][c0 + 1]; }
      short* dp = vT2 + ((size_t)(bq * 8 + hhg) * 64 + d0) * 768 + rrc + r8;
      *(b16x8*)dp         = *(b16x8*)t0;
      *(b16x8*)(dp + 768) = *(b16x8*)t1;
    }
  }
}

// ---------------------------------------------------------------------------
// Attention (R15): K staged in LDS (R12's win: K is consumed immediately),
// V loaded DIRECT from global per wave (R6-R11's proven path: V is consumed
// ~150-200cy after step start, so its L2 latency hides in-stream). Theory:
// attn's residual ~30us is LDS-PORT-bound — 10 b128 LDS ops/wave/step x
// 12 waves/CU serialize ~1440cy/step on the shared port; barrier/occupancy
// restructures (R13/R14) were flat because the port doesn't care. This
// halves LDS ops per step (10 -> 5) and halves staging traffic.
// ---------------------------------------------------------------------------
__global__ __launch_bounds__(256, 3) void attn_kernel(
    const short* __restrict__ q2, const short* __restrict__ k2,
    const short* __restrict__ vT2,
    const float* __restrict__ relT, const float* __restrict__ relP,
    short* __restrict__ yatt)
{
  __shared__ __align__(16) short Ks[2][2][2048]; // [buf][slot]: Ks0[32][32]|Ks1[32][32]
  __shared__ float btL[96];

  const float LOG2E = 1.44269504f;
  int tid = threadIdx.x;
  int w = tid >> 6, lane = tid & 63, n16 = lane & 15, quad = lane >> 4;
  int blk = blockIdx.x;                     // 768 = (16b * 6pgg) * 8h
  int h = blk & 7;                          // XCD-locality
  int g = blk >> 3;                         // 0..95
  int pgg = g % 6, b = g / 6;
  int pairq = pgg * 4 + w;                  // 0..23, unique per wave
  int qtA = pairq, qtB = 47 - pairq;
  int nAw = (qtA + 2) >> 1;                 // wave-local step counts
  int nBw = (qtB + 2) >> 1;
  int nBmax = 24 - 2 * pgg;                 // block-uniform (EVEN), = max nBw
  int nRounds = nBmax >> 1;

  if (tid < 96) btL[tid] = relT[(tid < 95 ? tid : 94) * 8 + h] * LOG2E;

  // swapped layout: reg r = key particle quad*4+r, lane n16 = q particle
  float bpT[4];
  #pragma unroll
  for (int r = 0; r < 4; ++r)
    bpT[r] = relP[(quad * 4 + r - n16 + 15) * 8 + h] * LOG2E;

  size_t bh = (size_t)(b * 8 + h);
  const short* qb = q2 + bh * 49152;
  const short* kb = k2 + bh * 49152;
  const short* vb = vT2 + bh * 49152;

  b16x8 qA0 = *(const b16x8*)(qb + (qtA * 16 + n16) * 64 + quad * 8);
  b16x8 qA1 = *(const b16x8*)(qb + (qtA * 16 + n16) * 64 + quad * 8 + 32);
  b16x8 qB0 = *(const b16x8*)(qb + (qtB * 16 + n16) * 64 + quad * 8);
  b16x8 qB1 = *(const b16x8*)(qb + (qtB * 16 + n16) * 64 + quad * 8 + 32);

  f32x4 zero4 = {0.f, 0.f, 0.f, 0.f};
  f32x4 oA[4], oB[4];
  float psA = 0.f, psB = 0.f;
  #pragma unroll
  for (int nt = 0; nt < 4; ++nt) { oA[nt] = zero4; oB[nt] = zero4; }

  // --- cooperative K staging: 256 threads cover K (32x64) per tile
  int krow = tid >> 3, kc8 = tid & 7;        // K: row 0..31, 16B chunk 0..7
  int kdst = (kc8 < 4 ? 0 : 1024) + krow * 32 + (kc8 & 3) * 8;   // Ks0 | Ks1
  b16x8 sk0, sk1;
  auto LOADR = [&](int kt2, b16x8& sk) {
    sk = *(const b16x8*)(kb + (size_t)(kt2 * 32 + krow) * 64 + kc8 * 8);
  };
  auto WRITE = [&](short* p, const b16x8& sk) {
    *(b16x8*)(p + kdst) = sk;
  };

  // exp2+bias on S^T tile pair, pack to the PV A-fragment in-register.
  auto exp_pack = [&](const f32x4& s0v, const f32x4& s1v, float bt0, float bt1,
                      float& ps) -> b16x8 {
    float e00 = ex2(s0v[0] + bt0 + bpT[0]);
    float e01 = ex2(s0v[1] + bt0 + bpT[1]);
    float e02 = ex2(s0v[2] + bt0 + bpT[2]);
    float e03 = ex2(s0v[3] + bt0 + bpT[3]);
    float e10 = ex2(s1v[0] + bt1 + bpT[0]);
    float e11 = ex2(s1v[1] + bt1 + bpT[1]);
    float e12 = ex2(s1v[2] + bt1 + bpT[2]);
    float e13 = ex2(s1v[3] + bt1 + bpT[3]);
    ps += ((e00 + e01) + (e02 + e03)) + ((e10 + e11) + (e12 + e13));
    unsigned p0 = cvt_pk_bf16(e00, e01);
    unsigned p1 = cvt_pk_bf16(e02, e03);
    unsigned p2 = cvt_pk_bf16(e10, e11);
    unsigned p3 = cvt_pk_bf16(e12, e13);
    u32x2 a02 = __builtin_amdgcn_permlane32_swap(p0, p2, false, false);
    u32x2 z02 = __builtin_amdgcn_permlane16_swap(a02.x, a02.y, false, false);
    u32x2 a13 = __builtin_amdgcn_permlane32_swap(p1, p3, false, false);
    u32x2 z13 = __builtin_amdgcn_permlane16_swap(a13.x, a13.y, false, false);
    union { unsigned u[4]; b16x8 v; } r;
    r.u[0] = z02.x;
    r.u[1] = z13.x;
    r.u[2] = z02.y;
    r.u[3] = z13.y;
    return r.v;
  };

  // one 32-key step: K frags from LDS slot p, V frags DIRECT from global
  // (issued first so L2 latency hides under QK-MFMA + exp + pack)
  auto step = [&](int kt2, const short* p) {
    bool doB = kt2 < nBw;
    if (!doB) return;
    bool doA = kt2 < nAw;
    // V direct loads: d = nt*16+n16, keys kt2*32 + quad*8..+7 (R11 path)
    const short* vp = vb + (size_t)n16 * 768 + kt2 * 32 + quad * 8;
    b16x8 vf0 = *(const b16x8*)vp;
    b16x8 vf1 = *(const b16x8*)(vp + 16 * 768);
    b16x8 vf2 = *(const b16x8*)(vp + 32 * 768);
    b16x8 vf3 = *(const b16x8*)(vp + 48 * 768);
    // K frags from LDS (conflict-free granule-sequential)
    b16x8 kf0 = *(const b16x8*)(p + n16 * 32 + quad * 8);
    b16x8 kf1 = *(const b16x8*)(p + 1024 + n16 * 32 + quad * 8);
    b16x8 kf2 = *(const b16x8*)(p + (16 + n16) * 32 + quad * 8);
    b16x8 kf3 = *(const b16x8*)(p + 1024 + (16 + n16) * 32 + quad * 8);

    int kt0 = kt2 * 2;
    f32x4 sB0 = zero4, sB1 = zero4;
    sB0 = __builtin_amdgcn_mfma_f32_16x16x32_bf16(kf0, qB0, sB0, 0, 0, 0);
    sB0 = __builtin_amdgcn_mfma_f32_16x16x32_bf16(kf1, qB1, sB0, 0, 0, 0);
    sB1 = __builtin_amdgcn_mfma_f32_16x16x32_bf16(kf2, qB0, sB1, 0, 0, 0);
    sB1 = __builtin_amdgcn_mfma_f32_16x16x32_bf16(kf3, qB1, sB1, 0, 0, 0);
    f32x4 sA0 = zero4, sA1 = zero4;
    if (doA) {
      sA0 = __builtin_amdgcn_mfma_f32_16x16x32_bf16(kf0, qA0, sA0, 0, 0, 0);
      sA0 = __builtin_amdgcn_mfma_f32_16x16x32_bf16(kf1, qA1, sA0, 0, 0, 0);
      sA1 = __builtin_amdgcn_mfma_f32_16x16x32_bf16(kf2, qA0, sA1, 0, 0, 0);
      sA1 = __builtin_amdgcn_mfma_f32_16x16x32_bf16(kf3, qA1, sA1, 0, 0, 0);
    }
    float btB0 = (kt0 <= qtB) ? btL[kt0 - qtB + 47] : -1e30f;
    float btB1 = (kt0 + 1 <= qtB) ? btL[kt0 + 1 - qtB + 47] : -1e30f;
    b16x8 pfB = exp_pack(sB0, sB1, btB0, btB1, psB);
    oB[0] = __builtin_amdgcn_mfma_f32_16x16x32_bf16(pfB, vf0, oB[0], 0, 0, 0);
    oB[1] = __builtin_amdgcn_mfma_f32_16x16x32_bf16(pfB, vf1, oB[1], 0, 0, 0);
    oB[2] = __builtin_amdgcn_mfma_f32_16x16x32_bf16(pfB, vf2, oB[2], 0, 0, 0);
    oB[3] = __builtin_amdgcn_mfma_f32_16x16x32_bf16(pfB, vf3, oB[3], 0, 0, 0);
    if (doA) {
      float btA0 = (kt0 <= qtA) ? btL[kt0 - qtA + 47] : -1e30f;
      float btA1 = (kt0 + 1 <= qtA) ? btL[kt0 + 1 - qtA + 47] : -1e30f;
      b16x8 pfA = exp_pack(sA0, sA1, btA0, btA1, psA);
      oA[0] = __builtin_amdgcn_mfma_f32_16x16x32_bf16(pfA, vf0, oA[0], 0, 0, 0);
      oA[1] = __builtin_amdgcn_mfma_f32_16x16x32_bf16(pfA, vf1, oA[1], 0, 0, 0);
      oA[2] = __builtin_amdgcn_mfma_f32_16x16x32_bf16(pfA, vf2, oA[2], 0, 0, 0);
      oA[3] = __builtin_amdgcn_mfma_f32_16x16x32_bf16(pfA, vf3, oA[3], 0, 0, 0);
    }
  };

  // prologue: stage K tiles 0,1 into buf 0 (nBmax >= 14, both always valid)
  LOADR(0, sk0);
  LOADR(1, sk1);
  WRITE(&Ks[0][0][0], sk0);
  WRITE(&Ks[0][1][0], sk1);
  __syncthreads();

  int buf = 0;
  for (int r = 0; r < nRounds; ++r) {
    bool more = (r + 1 < nRounds);           // block-uniform
    if (more) {                              // issue early: hides under compute
      LOADR(2 * r + 2, sk0);
      LOADR(2 * r + 3, sk1);
    }
    step(2 * r,     &Ks[buf][0][0]);
    step(2 * r + 1, &Ks[buf][1][0]);
    if (more) {                              // vmcnt wait lands HERE (after compute)
      WRITE(&Ks[buf ^ 1][0][0], sk0);
      WRITE(&Ks[buf ^ 1][1][0], sk1);
    }
    __syncthreads();                         // writes visible; reads of buf done
    buf ^= 1;
  }

  // denom: per-lane partial (q = n16, keys split across quads) -> full sum
  psA += __shfl_xor(psA, 16); psA += __shfl_xor(psA, 32);
  psB += __shfl_xor(psB, 16); psB += __shfl_xor(psB, 32);
  float invA = 1.0f / psA, invB = 1.0f / psB;
  float pnA[4], pnB[4];
  #pragma unroll
  for (int r = 0; r < 4; ++r) {
    pnA[r] = __shfl(invA, quad * 4 + r);
    pnB[r] = __shfl(invB, quad * 4 + r);
  }

  #pragma unroll
  for (int nt = 0; nt < 4; ++nt) {
    int c = h * 64 + nt * 16 + n16;
    #pragma unroll
    for (int r = 0; r < 4; ++r) {
      int qn = quad * 4 + r;
      yatt[((size_t)b * 768 + qn * 48 + qtA) * 512 + c] = f2b(oA[nt][r] * pnA[r]);
      yatt[((size_t)b * 768 + qn * 48 + qtB) * 512 + c] = f2b(oB[nt][r] * pnB[r]);
    }
  }
}

// ---------------------------------------------------------------------------
// proj (R14): 128x64 tiles -> grid 96x8 = 768 blocks (3 blocks/CU),
// global_load_lds staging, 12KB/buf double-buffered, conflict-free reads.
// ---------------------------------------------------------------------------
__global__ __launch_bounds__(256) void proj_kernel(
    const short* __restrict__ yatt, const short* __restrict__ WT,
    float* __restrict__ out)
{
  __shared__ __align__(16) short smem[12288];  // 24KB: 2 x (A 4096 | B 2048)
  int tid = threadIdx.x;
  int w = tid >> 6, lane = tid & 63, n16 = lane & 15, quad = lane >> 4;
  int row0 = blockIdx.x * 128;
  int ncol0 = blockIdx.y * 64;
  const short* Wt = WT + (size_t)3 * 262144;

  f32x4 zero4 = {0.f, 0.f, 0.f, 0.f};
  f32x4 acc[4][2];
  #pragma unroll
  for (int mt = 0; mt < 4; ++mt)
    #pragma unroll
    for (int nt = 0; nt < 2; ++nt) acc[mt][nt] = zero4;

  const short* gA[2];
  #pragma unroll
  for (int i = 0; i < 2; ++i) {
    int r16 = w + 4 * i;
    gA[i] = yatt + (size_t)(row0 + r16 * 16 + (lane >> 2)) * 512 + (lane & 3) * 8;
  }
  const short* gB = Wt + (size_t)(ncol0 + w * 16 + (lane >> 2)) * 512 + (lane & 3) * 8;
  int ldsoff = w * 512 + lane * 8;

  auto stage = [&](int buf, int kt) {
    short* As = smem + buf * 6144;
    short* Bs = As + 4096;
    #pragma unroll
    for (int i = 0; i < 2; ++i)
      gload16(gA[i] + kt * 32, As + i * 2048 + ldsoff);
    gload16(gB + kt * 32, Bs + ldsoff);
  };

  int wm = (w >> 1) * 64, wn = (w & 1) * 32;
  stage(0, 0);
  __syncthreads();
  int buf = 0;
  for (int kt = 0; kt < 16; ++kt) {
    if (kt < 15) stage(buf ^ 1, kt + 1);
    const short (*As)[32] = (const short(*)[32])(smem + buf * 6144);
    const short (*Bs)[32] = (const short(*)[32])(smem + buf * 6144 + 4096);
    b16x8 af[4], bf[2];
    #pragma unroll
    for (int mt = 0; mt < 4; ++mt) af[mt] = *(const b16x8*)&As[wm + mt * 16 + n16][quad * 8];
    #pragma unroll
    for (int nt = 0; nt < 2; ++nt) bf[nt] = *(const b16x8*)&Bs[wn + nt * 16 + n16][quad * 8];
    #pragma unroll
    for (int mt = 0; mt < 4; ++mt)
      #pragma unroll
      for (int nt = 0; nt < 2; ++nt)
        acc[mt][nt] = __builtin_amdgcn_mfma_f32_16x16x32_bf16(af[mt], bf[nt], acc[mt][nt], 0, 0, 0);
    __syncthreads();
    buf ^= 1;
  }

  #pragma unroll
  for (int mt = 0; mt < 4; ++mt) {
    int rowb = row0 + wm + mt * 16 + quad * 4;
    #pragma unroll
    for (int nt = 0; nt < 2; ++nt) {
      int colg = ncol0 + wn + nt * 16 + n16;
      #pragma unroll
      for (int r = 0; r < 4; ++r)
        out[(size_t)(rowb + r) * 512 + colg] = acc[mt][nt][r];
    }
  }
}

// ---------------------------------------------------------------------------
extern "C" void kernel_launch(void* const* d_in, const int* in_sizes, int n_in,
                              void* d_out, int out_size, void* d_ws, size_t ws_size,
                              hipStream_t stream) {
  const float* x    = (const float*)d_in[0];
  const float* Wq   = (const float*)d_in[1];
  const float* Wk   = (const float*)d_in[2];
  const float* Wv   = (const float*)d_in[3];
  const float* Wo   = (const float*)d_in[4];
  const float* relT = (const float*)d_in[5];
  const float* relP = (const float*)d_in[6];

  char* wsb = (char*)d_ws;
  const size_t SZ = (size_t)BL_ * C_ * 2;
  short* xb  = (short*)(wsb);
  short* WT  = (short*)(wsb + SZ);
  short* qb  = (short*)(wsb + SZ + 2097152);
  short* kb  = (short*)(wsb + 2 * SZ + 2097152);
  short* vTb = (short*)(wsb + 3 * SZ + 2097152);
  short* yat = (short*)(wsb + 4 * SZ + 2097152 + 4096);

  prep_kernel<<<dim3(4096), dim3(256), 0, stream>>>(x, Wq, Wk, Wv, Wo, xb, WT);
  qkv_kernel<<<dim3(96, 12), dim3(256), 0, stream>>>(xb, WT, qb, kb, vTb);
  attn_kernel<<<dim3(768), dim3(256), 0, stream>>>(qb, kb, vTb, relT, relP, yat);
  proj_kernel<<<dim3(96, 8), dim3(256), 0, stream>>>(yat, WT, (float*)d_out);
}

// Round 13
// 160.563 us; speedup vs baseline: 1.0456x; 1.0456x over previous
//
#include <hip/hip_runtime.h>
#include <hip/hip_bf16.h>
#include <math.h>

#define B_  16
#define N_  16
#define T_  48
#define C_  512
#define H_  8
#define HD_ 64
#define L_  768
#define BL_ 12288

typedef __attribute__((ext_vector_type(8))) short b16x8;
typedef __attribute__((ext_vector_type(4))) float f32x4;
typedef __attribute__((ext_vector_type(2))) unsigned int u32x2;

__device__ __forceinline__ short f2b(float f) {
  __hip_bfloat16 h = __float2bfloat16(f);
  return *reinterpret_cast<short*>(&h);
}
// packed f32x2 -> bf16x2 (RNE), single VALU op
__device__ __forceinline__ unsigned cvt_pk_bf16(float a, float b) {
  unsigned d;
  asm("v_cvt_pk_bf16_f32 %0, %1, %2" : "=v"(d) : "v"(a), "v"(b));
  return d;
}
// 2^x, single transcendental VALU op (biases/scales pre-folded by log2e)
__device__ __forceinline__ float ex2(float x) {
  float d;
  asm("v_exp_f32 %0, %1" : "=v"(d) : "v"(x));
  return d;
}
// async global->LDS, 16B per lane; dest must be linear base + lane*16
__device__ __forceinline__ void gload16(const void* g, void* l) {
  __builtin_amdgcn_global_load_lds(
      (const __attribute__((address_space(1))) void*)g,
      (__attribute__((address_space(3))) void*)l, 16, 0, 0);
}

// ---------------------------------------------------------------------------
// prep: blocks [0,3072) cast x fp32->bf16; blocks [3072,4096) cast+transpose
// weights into WT[mat][n][k] (Wq pre-scaled by log2(e)/8 for exp2 softmax).
// ---------------------------------------------------------------------------
__global__ __launch_bounds__(256) void prep_kernel(
    const float* __restrict__ x,
    const float* __restrict__ Wq, const float* __restrict__ Wk,
    const float* __restrict__ Wv, const float* __restrict__ Wo,
    short* __restrict__ xb, short* __restrict__ WT)
{
  __shared__ float tile[32][33];
  int blk = blockIdx.x;
  int tid = threadIdx.x;
  if (blk < 3072) {
    int i = blk * 256 + tid;
    const float4* src = (const float4*)(x + (size_t)i * 8);
    float4 a = src[0], b = src[1];
    short tmp[8] = {f2b(a.x), f2b(a.y), f2b(a.z), f2b(a.w),
                    f2b(b.x), f2b(b.y), f2b(b.z), f2b(b.w)};
    *(b16x8*)(xb + (size_t)i * 8) = *(b16x8*)tmp;
  } else {
    int idx = blk - 3072;
    int mat = idx >> 8, rem = idx & 255;
    const float* W = (mat == 0) ? Wq : (mat == 1) ? Wk : (mat == 2) ? Wv : Wo;
    float scale = (mat == 0) ? 0.18033688f : 1.0f;   // log2(e)/8
    int k0 = (rem >> 4) * 32, n0 = (rem & 15) * 32;
    int tx = tid & 31, ty = tid >> 5;
    for (int i = ty; i < 32; i += 8) tile[i][tx] = W[(size_t)(k0 + i) * 512 + n0 + tx];
    __syncthreads();
    short* dst = WT + (size_t)mat * 262144;
    for (int i = ty; i < 32; i += 8)
      dst[(size_t)(n0 + i) * 512 + k0 + tx] = f2b(tile[tx][i] * scale);
  }
}

// ---------------------------------------------------------------------------
// QKV GEMM (R11): global_load_lds width-16 double-buffered staging.
//   q2,k2: [b][h][t][n][d]   vT2: [b][h][d][t][n]
// ---------------------------------------------------------------------------
__global__ __launch_bounds__(256) void qkv_kernel(
    const short* __restrict__ xb, const short* __restrict__ WT,
    short* __restrict__ q2, short* __restrict__ k2, short* __restrict__ vT2)
{
  __shared__ __align__(16) short smem[16384];  // 32KB: [buf][A 4096 | B 4096]
  int tid = threadIdx.x;
  int w = tid >> 6, lane = tid & 63, n16 = lane & 15, quad = lane >> 4;
  int bm = blockIdx.x, bn = blockIdx.y;
  int mat = bn >> 2;
  int ncol0 = (bn & 3) * 128;
  const short* Wt = WT + (size_t)mat * 262144;
  int bq = bm / 6;
  int rr0 = (bm % 6) * 128;

  f32x4 zero4 = {0.f, 0.f, 0.f, 0.f};
  f32x4 acc[4][4];
  #pragma unroll
  for (int mt = 0; mt < 4; ++mt)
    #pragma unroll
    for (int nt = 0; nt < 4; ++nt) acc[mt][nt] = zero4;

  const short* gA[2];
  const short* gB[2];
  #pragma unroll
  for (int i = 0; i < 2; ++i) {
    int r16 = w + 4 * i;
    int rr = rr0 + r16 * 16 + (lane >> 2);
    int pt = rr >> 4, pn = rr & 15;          // permuted row -> l = pn*48+pt
    gA[i] = xb + ((size_t)bq * 768 + pn * 48 + pt) * 512 + (lane & 3) * 8;
    gB[i] = Wt + (size_t)(ncol0 + r16 * 16 + (lane >> 2)) * 512 + (lane & 3) * 8;
  }
  int ldsoff = (w) * 512 + lane * 8;         // shorts, within a 4096-short tile

  auto stage = [&](int buf, int kt) {
    short* As = smem + buf * 8192;
    short* Bs = As + 4096;
    #pragma unroll
    for (int i = 0; i < 2; ++i) {
      gload16(gA[i] + kt * 32, As + i * 2048 + ldsoff);
      gload16(gB[i] + kt * 32, Bs + i * 2048 + ldsoff);
    }
  };

  int wm = (w >> 1) * 64, wn = (w & 1) * 64;
  stage(0, 0);
  __syncthreads();                           // vmcnt(0) drain + barrier
  int buf = 0;
  for (int kt = 0; kt < 16; ++kt) {
    if (kt < 15) stage(buf ^ 1, kt + 1);
    const short (*As)[32] = (const short(*)[32])(smem + buf * 8192);
    const short (*Bs)[32] = (const short(*)[32])(smem + buf * 8192 + 4096);
    b16x8 af[4], bf[4];
    #pragma unroll
    for (int mt = 0; mt < 4; ++mt) af[mt] = *(const b16x8*)&As[wm + mt * 16 + n16][quad * 8];
    #pragma unroll
    for (int nt = 0; nt < 4; ++nt) bf[nt] = *(const b16x8*)&Bs[wn + nt * 16 + n16][quad * 8];
    #pragma unroll
    for (int mt = 0; mt < 4; ++mt)
      #pragma unroll
      for (int nt = 0; nt < 4; ++nt)
        acc[mt][nt] = __builtin_amdgcn_mfma_f32_16x16x32_bf16(af[mt], bf[nt], acc[mt][nt], 0, 0, 0);
    __syncthreads();                         // waves done reading + next tile landed
    buf ^= 1;
  }

  // epilogue: 4 chunks of 32 tile-rows staged through LDS, vector stores out
  short (*Ls)[136] = (short(*)[136])smem;    // 32 x 136 (pad: aligned, spread banks)
  for (int c = 0; c < 4; ++c) {
    __syncthreads();
    if ((w >> 1) == (c >> 1)) {              // waves owning rows 32c..32c+31
      int mtb = (c & 1) * 2;
      #pragma unroll
      for (int mi = 0; mi < 2; ++mi) {
        #pragma unroll
        for (int nt = 0; nt < 4; ++nt)
          #pragma unroll
          for (int r = 0; r < 4; ++r)
            Ls[mi * 16 + quad * 4 + r][wn + nt * 16 + n16] = f2b(acc[mtb + mi][nt][r]);
      }
    }
    __syncthreads();
    int rrc = rr0 + c * 32;
    if (mat != 2) {
      short* dst = (mat == 0) ? q2 : k2;
      int row = tid >> 3, c0 = (tid & 7) * 16;
      int hhg = (ncol0 + c0) >> 6, d0 = (ncol0 + c0) & 63;
      short* dp = dst + ((size_t)(bq * 8 + hhg) * 768 + rrc + row) * 64 + d0;
      *(b16x8*)dp       = *(b16x8*)&Ls[row][c0];
      *(b16x8*)(dp + 8) = *(b16x8*)&Ls[row][c0 + 8];
    } else {
      int cp = tid & 63, r8 = (tid >> 6) * 8;
      int c0 = 2 * cp;
      int hhg = (ncol0 + c0) >> 6, d0 = (ncol0 + c0) & 63;
      short t0[8], t1[8];
      #pragma unroll
      for (int j = 0; j < 8; ++j) { t0[j] = Ls[r8 + j][c0]; t1[j] = Ls[r8 + j][c0 + 1]; }
      short* dp = vT2 + ((size_t)(bq * 8 + hhg) * 64 + d0) * 768 + rrc + r8;
      *(b16x8*)dp         = *(b16x8*)t0;
      *(b16x8*)(dp + 768) = *(b16x8*)t1;
    }
  }
}

// ---------------------------------------------------------------------------
// Attention (R16): FOUR bands per wave, 2 waves/block. R12-R15 showed K+V
// belong in LDS, but all waves of a block read byte-identical fragment
// addresses -> port traffic = 8KB x waves per step for work ~ bands/wave.
// R13 paid 4KB of LDS port per chain-step; this halves it to 2KB by giving
// each wave pairs {base,base+1} (bands base,47-base,base+1,46-base).
// TLP drops to 6 waves/CU but each wave carries 4 independent band-chains
// of ILP. Staging = R12's proven 128-thread scheme. launch_bounds(128,2)
// caps regs at 256 (state ~190, no spill); residency is grid-limited.
// ---------------------------------------------------------------------------
__global__ __launch_bounds__(128, 2) void attn_kernel(
    const short* __restrict__ q2, const short* __restrict__ k2,
    const short* __restrict__ vT2,
    const float* __restrict__ relT, const float* __restrict__ relP,
    short* __restrict__ yatt)
{
  __shared__ __align__(16) short KV[2][4096];  // [buf]: Ks0[32][32]|Ks1[32][32]|Vs[64][32]
  __shared__ float btL[96];

  const float LOG2E = 1.44269504f;
  int tid = threadIdx.x;
  int w = tid >> 6, lane = tid & 63, n16 = lane & 15, quad = lane >> 4;
  int blk = blockIdx.x;                     // 768 = (16b * 6pgg) * 8h
  int h = blk & 7;                          // XCD-locality
  int g = blk >> 3;                         // 0..95
  int pgg = g % 6, b = g / 6;
  int base = pgg * 4 + 2 * w;               // this wave's two pairs: base, base+1
  int qtA0 = base,     qtB0 = 47 - base;
  int qtA1 = base + 1, qtB1 = 46 - base;
  int nA0 = (qtA0 + 2) >> 1, nA1 = (qtA1 + 2) >> 1;
  int nB0 = (qtB0 + 2) >> 1, nB1 = (qtB1 + 2) >> 1;
  int nBmax = 24 - 2 * pgg;                 // block-uniform loop bound (= w0's nB0)

  if (tid < 96) btL[tid] = relT[(tid < 95 ? tid : 94) * 8 + h] * LOG2E;

  // swapped layout: reg r = key particle quad*4+r, lane n16 = q particle
  float bpT[4];
  #pragma unroll
  for (int r = 0; r < 4; ++r)
    bpT[r] = relP[(quad * 4 + r - n16 + 15) * 8 + h] * LOG2E;

  size_t bh = (size_t)(b * 8 + h);
  const short* qb = q2 + bh * 49152;
  const short* kb = k2 + bh * 49152;
  const short* vb = vT2 + bh * 49152;

  b16x8 qA0_0 = *(const b16x8*)(qb + (qtA0 * 16 + n16) * 64 + quad * 8);
  b16x8 qA0_1 = *(const b16x8*)(qb + (qtA0 * 16 + n16) * 64 + quad * 8 + 32);
  b16x8 qA1_0 = *(const b16x8*)(qb + (qtA1 * 16 + n16) * 64 + quad * 8);
  b16x8 qA1_1 = *(const b16x8*)(qb + (qtA1 * 16 + n16) * 64 + quad * 8 + 32);
  b16x8 qB0_0 = *(const b16x8*)(qb + (qtB0 * 16 + n16) * 64 + quad * 8);
  b16x8 qB0_1 = *(const b16x8*)(qb + (qtB0 * 16 + n16) * 64 + quad * 8 + 32);
  b16x8 qB1_0 = *(const b16x8*)(qb + (qtB1 * 16 + n16) * 64 + quad * 8);
  b16x8 qB1_1 = *(const b16x8*)(qb + (qtB1 * 16 + n16) * 64 + quad * 8 + 32);

  f32x4 zero4 = {0.f, 0.f, 0.f, 0.f};
  f32x4 oA0[4], oA1[4], oB0[4], oB1[4];
  float psA0 = 0.f, psA1 = 0.f, psB0 = 0.f, psB1 = 0.f;
  #pragma unroll
  for (int nt = 0; nt < 4; ++nt) {
    oA0[nt] = zero4; oA1[nt] = zero4; oB0[nt] = zero4; oB1[nt] = zero4;
  }

  // --- cooperative staging (R12 scheme): 128 threads, K(32x64)+V(64x32)
  int krow = tid >> 3, kc8 = tid & 7;        // K rows krow, krow+16
  int vd   = tid >> 2, vkc = tid & 3;        // V d vd, vd+32
  int kdst = (kc8 < 4 ? 0 : 1024) + krow * 32 + (kc8 & 3) * 8;   // Ks0 | Ks1
  int vdst = 2048 + vd * 32 + vkc * 8;                           // Vs
  b16x8 s0, s1, s2, s3;
  auto LOADR = [&](int kt2) {
    const short* kq = kb + (size_t)(kt2 * 32 + krow) * 64 + kc8 * 8;
    s0 = *(const b16x8*)kq;
    s1 = *(const b16x8*)(kq + 16 * 64);
    const short* vq = vb + (size_t)vd * 768 + kt2 * 32 + vkc * 8;
    s2 = *(const b16x8*)vq;
    s3 = *(const b16x8*)(vq + (size_t)32 * 768);
  };
  auto WRITE = [&](int buf) {
    short* p = KV[buf];
    *(b16x8*)(p + kdst)        = s0;
    *(b16x8*)(p + kdst + 512)  = s1;
    *(b16x8*)(p + vdst)        = s2;
    *(b16x8*)(p + vdst + 1024) = s3;
  };

  // exp2+bias, pack to PV A-fragment in-register.
  auto exp_pack = [&](const f32x4& s0v, const f32x4& s1v, float bt0, float bt1,
                      float& ps) -> b16x8 {
    float e00 = ex2(s0v[0] + bt0 + bpT[0]);
    float e01 = ex2(s0v[1] + bt0 + bpT[1]);
    float e02 = ex2(s0v[2] + bt0 + bpT[2]);
    float e03 = ex2(s0v[3] + bt0 + bpT[3]);
    float e10 = ex2(s1v[0] + bt1 + bpT[0]);
    float e11 = ex2(s1v[1] + bt1 + bpT[1]);
    float e12 = ex2(s1v[2] + bt1 + bpT[2]);
    float e13 = ex2(s1v[3] + bt1 + bpT[3]);
    ps += ((e00 + e01) + (e02 + e03)) + ((e10 + e11) + (e12 + e13));
    unsigned p0 = cvt_pk_bf16(e00, e01);
    unsigned p1 = cvt_pk_bf16(e02, e03);
    unsigned p2 = cvt_pk_bf16(e10, e11);
    unsigned p3 = cvt_pk_bf16(e12, e13);
    u32x2 a02 = __builtin_amdgcn_permlane32_swap(p0, p2, false, false);
    u32x2 z02 = __builtin_amdgcn_permlane16_swap(a02.x, a02.y, false, false);
    u32x2 a13 = __builtin_amdgcn_permlane32_swap(p1, p3, false, false);
    u32x2 z13 = __builtin_amdgcn_permlane16_swap(a13.x, a13.y, false, false);
    union { unsigned u[4]; b16x8 v; } r;
    r.u[0] = z02.x;
    r.u[1] = z13.x;
    r.u[2] = z02.y;
    r.u[3] = z13.y;
    return r.v;
  };

  // one band's QK (4 MFMA) into s0v,s1v
  auto qk = [&](const b16x8* kf, const b16x8& q0, const b16x8& q1,
                f32x4& sv0, f32x4& sv1) {
    sv0 = zero4; sv1 = zero4;
    sv0 = __builtin_amdgcn_mfma_f32_16x16x32_bf16(kf[0], q0, sv0, 0, 0, 0);
    sv0 = __builtin_amdgcn_mfma_f32_16x16x32_bf16(kf[1], q1, sv0, 0, 0, 0);
    sv1 = __builtin_amdgcn_mfma_f32_16x16x32_bf16(kf[2], q0, sv1, 0, 0, 0);
    sv1 = __builtin_amdgcn_mfma_f32_16x16x32_bf16(kf[3], q1, sv1, 0, 0, 0);
  };
  auto pv = [&](const b16x8& pf, const b16x8* vf, f32x4* o) {
    o[0] = __builtin_amdgcn_mfma_f32_16x16x32_bf16(pf, vf[0], o[0], 0, 0, 0);
    o[1] = __builtin_amdgcn_mfma_f32_16x16x32_bf16(pf, vf[1], o[1], 0, 0, 0);
    o[2] = __builtin_amdgcn_mfma_f32_16x16x32_bf16(pf, vf[2], o[2], 0, 0, 0);
    o[3] = __builtin_amdgcn_mfma_f32_16x16x32_bf16(pf, vf[3], o[3], 0, 0, 0);
  };

  // prologue: stage tile 0
  LOADR(0);
  WRITE(0);
  __syncthreads();

  int buf = 0;
  for (int kt2 = 0; kt2 < nBmax; ++kt2) {
    bool more = (kt2 + 1 < nBmax);           // block-uniform
    if (more) LOADR(kt2 + 1);                // issue early: hides under compute

    bool dB0 = kt2 < nB0, dB1 = kt2 < nB1;   // wave-uniform guards
    bool dA1 = kt2 < nA1, dA0 = kt2 < nA0;
    const short* p = KV[buf];
    b16x8 kf[4], vf[4];
    if (dB0) {
      kf[0] = *(const b16x8*)(p + n16 * 32 + quad * 8);
      kf[1] = *(const b16x8*)(p + 1024 + n16 * 32 + quad * 8);
      kf[2] = *(const b16x8*)(p + (16 + n16) * 32 + quad * 8);
      kf[3] = *(const b16x8*)(p + 1024 + (16 + n16) * 32 + quad * 8);
      vf[0] = *(const b16x8*)(p + 2048 + n16 * 32 + quad * 8);
      vf[1] = *(const b16x8*)(p + 2048 + (16 + n16) * 32 + quad * 8);
      vf[2] = *(const b16x8*)(p + 2048 + (32 + n16) * 32 + quad * 8);
      vf[3] = *(const b16x8*)(p + 2048 + (48 + n16) * 32 + quad * 8);

      int kt0 = kt2 * 2;
      // QK for all active bands first (independent MFMA chains)
      f32x4 sB0a, sB0b, sB1a, sB1b, sA0a, sA0b, sA1a, sA1b;
      qk(kf, qB0_0, qB0_1, sB0a, sB0b);
      if (dB1) qk(kf, qB1_0, qB1_1, sB1a, sB1b);
      if (dA1) qk(kf, qA1_0, qA1_1, sA1a, sA1b);
      if (dA0) qk(kf, qA0_0, qA0_1, sA0a, sA0b);

      // exp+pack+PV per band
      {
        float bt0 = (kt0 <= qtB0) ? btL[kt0 - qtB0 + 47] : -1e30f;
        float bt1 = (kt0 + 1 <= qtB0) ? btL[kt0 + 1 - qtB0 + 47] : -1e30f;
        pv(exp_pack(sB0a, sB0b, bt0, bt1, psB0), vf, oB0);
      }
      if (dB1) {
        float bt0 = (kt0 <= qtB1) ? btL[kt0 - qtB1 + 47] : -1e30f;
        float bt1 = (kt0 + 1 <= qtB1) ? btL[kt0 + 1 - qtB1 + 47] : -1e30f;
        pv(exp_pack(sB1a, sB1b, bt0, bt1, psB1), vf, oB1);
      }
      if (dA1) {
        float bt0 = (kt0 <= qtA1) ? btL[kt0 - qtA1 + 47] : -1e30f;
        float bt1 = (kt0 + 1 <= qtA1) ? btL[kt0 + 1 - qtA1 + 47] : -1e30f;
        pv(exp_pack(sA1a, sA1b, bt0, bt1, psA1), vf, oA1);
      }
      if (dA0) {
        float bt0 = (kt0 <= qtA0) ? btL[kt0 - qtA0 + 47] : -1e30f;
        float bt1 = (kt0 + 1 <= qtA0) ? btL[kt0 + 1 - qtA0 + 47] : -1e30f;
        pv(exp_pack(sA0a, sA0b, bt0, bt1, psA0), vf, oA0);
      }
    }

    if (more) WRITE(buf ^ 1);                // vmcnt wait lands HERE (after compute)
    __syncthreads();                         // writes visible; reads of buf done
    buf ^= 1;
  }

  // denom + output per band
  auto finish = [&](float ps, f32x4* o, int qt) {
    ps += __shfl_xor(ps, 16);
    ps += __shfl_xor(ps, 32);
    float inv = 1.0f / ps;
    float pn[4];
    #pragma unroll
    for (int r = 0; r < 4; ++r) pn[r] = __shfl(inv, quad * 4 + r);
    #pragma unroll
    for (int nt = 0; nt < 4; ++nt) {
      int c = h * 64 + nt * 16 + n16;
      #pragma unroll
      for (int r = 0; r < 4; ++r) {
        int qn = quad * 4 + r;
        yatt[((size_t)b * 768 + qn * 48 + qt) * 512 + c] = f2b(o[nt][r] * pn[r]);
      }
    }
  };
  finish(psB0, oB0, qtB0);
  finish(psB1, oB1, qtB1);
  finish(psA1, oA1, qtA1);
  finish(psA0, oA0, qtA0);
}

// ---------------------------------------------------------------------------
// proj (R11 config — best measured): yatt(12288x512,bf16) @ WoT -> out fp32,
// global_load_lds double-buffered staging, 128x128 tiles, grid 96x4.
// ---------------------------------------------------------------------------
__global__ __launch_bounds__(256) void proj_kernel(
    const short* __restrict__ yatt, const short* __restrict__ WT,
    float* __restrict__ out)
{
  __shared__ __align__(16) short smem[16384];  // 32KB double buffer
  int tid = threadIdx.x;
  int w = tid >> 6, lane = tid & 63, n16 = lane & 15, quad = lane >> 4;
  int row0 = blockIdx.x * 128;
  int ncol0 = blockIdx.y * 128;
  const short* Wt = WT + (size_t)3 * 262144;

  f32x4 zero4 = {0.f, 0.f, 0.f, 0.f};
  f32x4 acc[4][4];
  #pragma unroll
  for (int mt = 0; mt < 4; ++mt)
    #pragma unroll
    for (int nt = 0; nt < 4; ++nt) acc[mt][nt] = zero4;

  const short* gA[2];
  const short* gB[2];
  #pragma unroll
  for (int i = 0; i < 2; ++i) {
    int r16 = w + 4 * i;
    gA[i] = yatt + (size_t)(row0 + r16 * 16 + (lane >> 2)) * 512 + (lane & 3) * 8;
    gB[i] = Wt + (size_t)(ncol0 + r16 * 16 + (lane >> 2)) * 512 + (lane & 3) * 8;
  }
  int ldsoff = w * 512 + lane * 8;

  auto stage = [&](int buf, int kt) {
    short* As = smem + buf * 8192;
    short* Bs = As + 4096;
    #pragma unroll
    for (int i = 0; i < 2; ++i) {
      gload16(gA[i] + kt * 32, As + i * 2048 + ldsoff);
      gload16(gB[i] + kt * 32, Bs + i * 2048 + ldsoff);
    }
  };

  int wm = (w >> 1) * 64, wn = (w & 1) * 64;
  stage(0, 0);
  __syncthreads();
  int buf = 0;
  for (int kt = 0; kt < 16; ++kt) {
    if (kt < 15) stage(buf ^ 1, kt + 1);
    const short (*As)[32] = (const short(*)[32])(smem + buf * 8192);
    const short (*Bs)[32] = (const short(*)[32])(smem + buf * 8192 + 4096);
    b16x8 af[4], bf[4];
    #pragma unroll
    for (int mt = 0; mt < 4; ++mt) af[mt] = *(const b16x8*)&As[wm + mt * 16 + n16][quad * 8];
    #pragma unroll
    for (int nt = 0; nt < 4; ++nt) bf[nt] = *(const b16x8*)&Bs[wn + nt * 16 + n16][quad * 8];
    #pragma unroll
    for (int mt = 0; mt < 4; ++mt)
      #pragma unroll
      for (int nt = 0; nt < 4; ++nt)
        acc[mt][nt] = __builtin_amdgcn_mfma_f32_16x16x32_bf16(af[mt], bf[nt], acc[mt][nt], 0, 0, 0);
    __syncthreads();
    buf ^= 1;
  }

  #pragma unroll
  for (int mt = 0; mt < 4; ++mt) {
    int rowb = row0 + wm + mt * 16 + quad * 4;
    #pragma unroll
    for (int nt = 0; nt < 4; ++nt) {
      int colg = ncol0 + wn + nt * 16 + n16;
      #pragma unroll
      for (int r = 0; r < 4; ++r)
        out[(size_t)(rowb + r) * 512 + colg] = acc[mt][nt][r];
    }
  }
}

// ---------------------------------------------------------------------------
extern "C" void kernel_launch(void* const* d_in, const int* in_sizes, int n_in,
                              void* d_out, int out_size, void* d_ws, size_t ws_size,
                              hipStream_t stream) {
  const float* x    = (const float*)d_in[0];
  const float* Wq   = (const float*)d_in[1];
  const float* Wk   = (const float*)d_in[2];
  const float* Wv   = (const float*)d_in[3];
  const float* Wo   = (const float*)d_in[4];
  const float* relT = (const float*)d_in[5];
  const float* relP = (const float*)d_in[6];

  char* wsb = (char*)d_ws;
  const size_t SZ = (size_t)BL_ * C_ * 2;
  short* xb  = (short*)(wsb);
  short* WT  = (short*)(wsb + SZ);
  short* qb  = (short*)(wsb + SZ + 2097152);
  short* kb  = (short*)(wsb + 2 * SZ + 2097152);
  short* vTb = (short*)(wsb + 3 * SZ + 2097152);
  short* yat = (short*)(wsb + 4 * SZ + 2097152 + 4096);

  prep_kernel<<<dim3(4096), dim3(256), 0, stream>>>(x, Wq, Wk, Wv, Wo, xb, WT);
  qkv_kernel<<<dim3(96, 12), dim3(256), 0, stream>>>(xb, WT, qb, kb, vTb);
  attn_kernel<<<dim3(768), dim3(128), 0, stream>>>(qb, kb, vTb, relT, relP, yat);
  proj_kernel<<<dim3(96, 4), dim3(256), 0, stream>>>(yat, WT, (float*)d_out);
}

// Round 15
// 157.000 us; speedup vs baseline: 1.0693x; 1.0227x over previous
//
#include <hip/hip_runtime.h>
#include <hip/hip_bf16.h>
#include <math.h>

#define B_  16
#define N_  16
#define T_  48
#define C_  512
#define H_  8
#define HD_ 64
#define L_  768
#define BL_ 12288

typedef __attribute__((ext_vector_type(8))) short b16x8;
typedef __attribute__((ext_vector_type(4))) float f32x4;
typedef __attribute__((ext_vector_type(2))) unsigned int u32x2;

__device__ __forceinline__ short f2b(float f) {
  __hip_bfloat16 h = __float2bfloat16(f);
  return *reinterpret_cast<short*>(&h);
}
// packed f32x2 -> bf16x2 (RNE), single VALU op
__device__ __forceinline__ unsigned cvt_pk_bf16(float a, float b) {
  unsigned d;
  asm("v_cvt_pk_bf16_f32 %0, %1, %2" : "=v"(d) : "v"(a), "v"(b));
  return d;
}
// 2^x, single transcendental VALU op (biases/scales pre-folded by log2e)
__device__ __forceinline__ float ex2(float x) {
  float d;
  asm("v_exp_f32 %0, %1" : "=v"(d) : "v"(x));
  return d;
}
// async global->LDS, 16B per lane; dest must be linear base + lane*16
__device__ __forceinline__ void gload16(const void* g, void* l) {
  __builtin_amdgcn_global_load_lds(
      (const __attribute__((address_space(1))) void*)g,
      (__attribute__((address_space(3))) void*)l, 16, 0, 0);
}

// ---------------------------------------------------------------------------
// prep: blocks [0,3072) cast x fp32->bf16; blocks [3072,4096) cast+transpose
// weights into WT[mat][n][k] (Wq pre-scaled by log2(e)/8 for exp2 softmax).
// ---------------------------------------------------------------------------
__global__ __launch_bounds__(256) void prep_kernel(
    const float* __restrict__ x,
    const float* __restrict__ Wq, const float* __restrict__ Wk,
    const float* __restrict__ Wv, const float* __restrict__ Wo,
    short* __restrict__ xb, short* __restrict__ WT)
{
  __shared__ float tile[32][33];
  int blk = blockIdx.x;
  int tid = threadIdx.x;
  if (blk < 3072) {
    int i = blk * 256 + tid;
    const float4* src = (const float4*)(x + (size_t)i * 8);
    float4 a = src[0], b = src[1];
    short tmp[8] = {f2b(a.x), f2b(a.y), f2b(a.z), f2b(a.w),
                    f2b(b.x), f2b(b.y), f2b(b.z), f2b(b.w)};
    *(b16x8*)(xb + (size_t)i * 8) = *(b16x8*)tmp;
  } else {
    int idx = blk - 3072;
    int mat = idx >> 8, rem = idx & 255;
    const float* W = (mat == 0) ? Wq : (mat == 1) ? Wk : (mat == 2) ? Wv : Wo;
    float scale = (mat == 0) ? 0.18033688f : 1.0f;   // log2(e)/8
    int k0 = (rem >> 4) * 32, n0 = (rem & 15) * 32;
    int tx = tid & 31, ty = tid >> 5;
    for (int i = ty; i < 32; i += 8) tile[i][tx] = W[(size_t)(k0 + i) * 512 + n0 + tx];
    __syncthreads();
    short* dst = WT + (size_t)mat * 262144;
    for (int i = ty; i < 32; i += 8)
      dst[(size_t)(n0 + i) * 512 + k0 + tx] = f2b(tile[tx][i] * scale);
  }
}

// ---------------------------------------------------------------------------
// QKV GEMM (R11): global_load_lds width-16 double-buffered staging.
//   q2,k2: [b][h][t][n][d]   vT2: [b][h][d][t][n]
// ---------------------------------------------------------------------------
__global__ __launch_bounds__(256) void qkv_kernel(
    const short* __restrict__ xb, const short* __restrict__ WT,
    short* __restrict__ q2, short* __restrict__ k2, short* __restrict__ vT2)
{
  __shared__ __align__(16) short smem[16384];  // 32KB: [buf][A 4096 | B 4096]
  int tid = threadIdx.x;
  int w = tid >> 6, lane = tid & 63, n16 = lane & 15, quad = lane >> 4;
  int bm = blockIdx.x, bn = blockIdx.y;
  int mat = bn >> 2;
  int ncol0 = (bn & 3) * 128;
  const short* Wt = WT + (size_t)mat * 262144;
  int bq = bm / 6;
  int rr0 = (bm % 6) * 128;

  f32x4 zero4 = {0.f, 0.f, 0.f, 0.f};
  f32x4 acc[4][4];
  #pragma unroll
  for (int mt = 0; mt < 4; ++mt)
    #pragma unroll
    for (int nt = 0; nt < 4; ++nt) acc[mt][nt] = zero4;

  const short* gA[2];
  const short* gB[2];
  #pragma unroll
  for (int i = 0; i < 2; ++i) {
    int r16 = w + 4 * i;
    int rr = rr0 + r16 * 16 + (lane >> 2);
    int pt = rr >> 4, pn = rr & 15;          // permuted row -> l = pn*48+pt
    gA[i] = xb + ((size_t)bq * 768 + pn * 48 + pt) * 512 + (lane & 3) * 8;
    gB[i] = Wt + (size_t)(ncol0 + r16 * 16 + (lane >> 2)) * 512 + (lane & 3) * 8;
  }
  int ldsoff = (w) * 512 + lane * 8;         // shorts, within a 4096-short tile

  auto stage = [&](int buf, int kt) {
    short* As = smem + buf * 8192;
    short* Bs = As + 4096;
    #pragma unroll
    for (int i = 0; i < 2; ++i) {
      gload16(gA[i] + kt * 32, As + i * 2048 + ldsoff);
      gload16(gB[i] + kt * 32, Bs + i * 2048 + ldsoff);
    }
  };

  int wm = (w >> 1) * 64, wn = (w & 1) * 64;
  stage(0, 0);
  __syncthreads();                           // vmcnt(0) drain + barrier
  int buf = 0;
  for (int kt = 0; kt < 16; ++kt) {
    if (kt < 15) stage(buf ^ 1, kt + 1);
    const short (*As)[32] = (const short(*)[32])(smem + buf * 8192);
    const short (*Bs)[32] = (const short(*)[32])(smem + buf * 8192 + 4096);
    b16x8 af[4], bf[4];
    #pragma unroll
    for (int mt = 0; mt < 4; ++mt) af[mt] = *(const b16x8*)&As[wm + mt * 16 + n16][quad * 8];
    #pragma unroll
    for (int nt = 0; nt < 4; ++nt) bf[nt] = *(const b16x8*)&Bs[wn + nt * 16 + n16][quad * 8];
    #pragma unroll
    for (int mt = 0; mt < 4; ++mt)
      #pragma unroll
      for (int nt = 0; nt < 4; ++nt)
        acc[mt][nt] = __builtin_amdgcn_mfma_f32_16x16x32_bf16(af[mt], bf[nt], acc[mt][nt], 0, 0, 0);
    __syncthreads();                         // waves done reading + next tile landed
    buf ^= 1;
  }

  // epilogue: 4 chunks of 32 tile-rows staged through LDS, vector stores out
  short (*Ls)[136] = (short(*)[136])smem;    // 32 x 136 (pad: aligned, spread banks)
  for (int c = 0; c < 4; ++c) {
    __syncthreads();
    if ((w >> 1) == (c >> 1)) {              // waves owning rows 32c..32c+31
      int mtb = (c & 1) * 2;
      #pragma unroll
      for (int mi = 0; mi < 2; ++mi) {
        #pragma unroll
        for (int nt = 0; nt < 4; ++nt)
          #pragma unroll
          for (int r = 0; r < 4; ++r)
            Ls[mi * 16 + quad * 4 + r][wn + nt * 16 + n16] = f2b(acc[mtb + mi][nt][r]);
      }
    }
    __syncthreads();
    int rrc = rr0 + c * 32;
    if (mat != 2) {
      short* dst = (mat == 0) ? q2 : k2;
      int row = tid >> 3, c0 = (tid & 7) * 16;
      int hhg = (ncol0 + c0) >> 6, d0 = (ncol0 + c0) & 63;
      short* dp = dst + ((size_t)(bq * 8 + hhg) * 768 + rrc + row) * 64 + d0;
      *(b16x8*)dp       = *(b16x8*)&Ls[row][c0];
      *(b16x8*)(dp + 8) = *(b16x8*)&Ls[row][c0 + 8];
    } else {
      int cp = tid & 63, r8 = (tid >> 6) * 8;
      int c0 = 2 * cp;
      int hhg = (ncol0 + c0) >> 6, d0 = (ncol0 + c0) & 63;
      short t0[8], t1[8];
      #pragma unroll
      for (int j = 0; j < 8; ++j) { t0[j] = Ls[r8 + j][c0]; t1[j] = Ls[r8 + j][c0 + 1]; }
      short* dp = vT2 + ((size_t)(bq * 8 + hhg) * 64 + d0) * 768 + rrc + r8;
      *(b16x8*)dp         = *(b16x8*)t0;
      *(b16x8*)(dp + 768) = *(b16x8*)t1;
    }
  }
}

// ---------------------------------------------------------------------------
// Attention (R13 revert — best measured, 156.8 µs total): 4 waves/block,
// two pg-pairs sharing one K/V LDS staging (256 threads cover the 8KB tile,
// 1 load each), double-buffered, one barrier/step. Wave w handles
// pair = 4*pgg + w; block-uniform nBmax loop with wave-uniform doB/doA
// guards. T5 setprio around MFMA clusters. launch_bounds(256,4).
// ---------------------------------------------------------------------------
__global__ __launch_bounds__(256, 4) void attn_kernel(
    const short* __restrict__ q2, const short* __restrict__ k2,
    const short* __restrict__ vT2,
    const float* __restrict__ relT, const float* __restrict__ relP,
    short* __restrict__ yatt)
{
  __shared__ __align__(16) short KV[2][4096];  // [buf]: Ks0[32][32] | Ks1[32][32] | Vs[64][32]
  __shared__ float btL[96];

  const float LOG2E = 1.44269504f;
  int tid = threadIdx.x;
  int w = tid >> 6, lane = tid & 63, n16 = lane & 15, quad = lane >> 4;
  int blk = blockIdx.x;                     // 768 = (16b * 6pgg) * 8h
  int h = blk & 7;                          // XCD-locality
  int g = blk >> 3;                         // 0..95
  int pgg = g % 6, b = g / 6;
  int pairq = pgg * 4 + w;                  // 0..23, unique per wave
  int qtA = pairq, qtB = 47 - pairq;
  int nAw = (qtA + 2) >> 1;                 // wave-local step counts
  int nBw = (qtB + 2) >> 1;
  int nBmax = 24 - 2 * pgg;                 // block-uniform loop bound (= max nBw)

  if (tid < 96) btL[tid] = relT[(tid < 95 ? tid : 94) * 8 + h] * LOG2E;

  // swapped layout: reg r = key particle quad*4+r, lane n16 = q particle
  float bpT[4];
  #pragma unroll
  for (int r = 0; r < 4; ++r)
    bpT[r] = relP[(quad * 4 + r - n16 + 15) * 8 + h] * LOG2E;

  size_t bh = (size_t)(b * 8 + h);
  const short* qb = q2 + bh * 49152;
  const short* kb = k2 + bh * 49152;
  const short* vb = vT2 + bh * 49152;

  b16x8 qA0 = *(const b16x8*)(qb + (qtA * 16 + n16) * 64 + quad * 8);
  b16x8 qA1 = *(const b16x8*)(qb + (qtA * 16 + n16) * 64 + quad * 8 + 32);
  b16x8 qB0 = *(const b16x8*)(qb + (qtB * 16 + n16) * 64 + quad * 8);
  b16x8 qB1 = *(const b16x8*)(qb + (qtB * 16 + n16) * 64 + quad * 8 + 32);

  f32x4 zero4 = {0.f, 0.f, 0.f, 0.f};
  f32x4 oA[4], oB[4];
  float psA = 0.f, psB = 0.f;
  #pragma unroll
  for (int nt = 0; nt < 4; ++nt) { oA[nt] = zero4; oB[nt] = zero4; }

  // --- cooperative staging: 256 threads cover K (32x64) + V (64x32), 1 load each
  int krow = tid >> 3, kc8 = tid & 7;        // K: row 0..31, 16B chunk 0..7
  int vd   = tid >> 2, vkc = tid & 3;        // V: d 0..63, 16B chunk 0..3
  int kdst = (kc8 < 4 ? 0 : 1024) + krow * 32 + (kc8 & 3) * 8;   // Ks0 | Ks1 (d-halves)
  int vdst = 2048 + vd * 32 + vkc * 8;                           // Vs
  b16x8 s0, s2;
  auto LOADR = [&](int kt2) {
    s0 = *(const b16x8*)(kb + (size_t)(kt2 * 32 + krow) * 64 + kc8 * 8);
    s2 = *(const b16x8*)(vb + (size_t)vd * 768 + kt2 * 32 + vkc * 8);
  };
  auto WRITE = [&](int buf) {
    *(b16x8*)(KV[buf] + kdst) = s0;
    *(b16x8*)(KV[buf] + vdst) = s2;
  };

  // exp2 + bias on S^T tile pair, pack to the PV A-fragment in-register.
  auto exp_pack = [&](const f32x4& s0v, const f32x4& s1v, float bt0, float bt1,
                      float& ps) -> b16x8 {
    float e00 = ex2(s0v[0] + bt0 + bpT[0]);
    float e01 = ex2(s0v[1] + bt0 + bpT[1]);
    float e02 = ex2(s0v[2] + bt0 + bpT[2]);
    float e03 = ex2(s0v[3] + bt0 + bpT[3]);
    float e10 = ex2(s1v[0] + bt1 + bpT[0]);
    float e11 = ex2(s1v[1] + bt1 + bpT[1]);
    float e12 = ex2(s1v[2] + bt1 + bpT[2]);
    float e13 = ex2(s1v[3] + bt1 + bpT[3]);
    ps += ((e00 + e01) + (e02 + e03)) + ((e10 + e11) + (e12 + e13));
    unsigned p0 = cvt_pk_bf16(e00, e01);
    unsigned p1 = cvt_pk_bf16(e02, e03);
    unsigned p2 = cvt_pk_bf16(e10, e11);
    unsigned p3 = cvt_pk_bf16(e12, e13);
    u32x2 a02 = __builtin_amdgcn_permlane32_swap(p0, p2, false, false);
    u32x2 z02 = __builtin_amdgcn_permlane16_swap(a02.x, a02.y, false, false);
    u32x2 a13 = __builtin_amdgcn_permlane32_swap(p1, p3, false, false);
    u32x2 z13 = __builtin_amdgcn_permlane16_swap(a13.x, a13.y, false, false);
    union { unsigned u[4]; b16x8 v; } r;
    r.u[0] = z02.x;
    r.u[1] = z13.x;
    r.u[2] = z02.y;
    r.u[3] = z13.y;
    return r.v;
  };

  // prologue: stage tile 0 (also covers btL visibility)
  LOADR(0);
  WRITE(0);
  __syncthreads();

  int buf = 0;
  for (int kt2 = 0; kt2 < nBmax; ++kt2) {
    bool more = (kt2 + 1 < nBmax);           // block-uniform
    if (more) LOADR(kt2 + 1);                // issue early: latency hides under compute

    bool doB = kt2 < nBw;                    // wave-uniform
    bool doA = kt2 < nAw;                    // wave-uniform, doA => doB
    if (doB) {
      const short* p = KV[buf];
      b16x8 kf0 = *(const b16x8*)(p + n16 * 32 + quad * 8);
      b16x8 kf1 = *(const b16x8*)(p + 1024 + n16 * 32 + quad * 8);
      b16x8 kf2 = *(const b16x8*)(p + (16 + n16) * 32 + quad * 8);
      b16x8 kf3 = *(const b16x8*)(p + 1024 + (16 + n16) * 32 + quad * 8);
      b16x8 vf0 = *(const b16x8*)(p + 2048 + n16 * 32 + quad * 8);
      b16x8 vf1 = *(const b16x8*)(p + 2048 + (16 + n16) * 32 + quad * 8);
      b16x8 vf2 = *(const b16x8*)(p + 2048 + (32 + n16) * 32 + quad * 8);
      b16x8 vf3 = *(const b16x8*)(p + 2048 + (48 + n16) * 32 + quad * 8);

      int kt0 = kt2 * 2;
      __builtin_amdgcn_s_setprio(1);
      f32x4 sB0 = zero4, sB1 = zero4;
      sB0 = __builtin_amdgcn_mfma_f32_16x16x32_bf16(kf0, qB0, sB0, 0, 0, 0);
      sB0 = __builtin_amdgcn_mfma_f32_16x16x32_bf16(kf1, qB1, sB0, 0, 0, 0);
      sB1 = __builtin_amdgcn_mfma_f32_16x16x32_bf16(kf2, qB0, sB1, 0, 0, 0);
      sB1 = __builtin_amdgcn_mfma_f32_16x16x32_bf16(kf3, qB1, sB1, 0, 0, 0);
      f32x4 sA0 = zero4, sA1 = zero4;
      if (doA) {
        sA0 = __builtin_amdgcn_mfma_f32_16x16x32_bf16(kf0, qA0, sA0, 0, 0, 0);
        sA0 = __builtin_amdgcn_mfma_f32_16x16x32_bf16(kf1, qA1, sA0, 0, 0, 0);
        sA1 = __builtin_amdgcn_mfma_f32_16x16x32_bf16(kf2, qA0, sA1, 0, 0, 0);
        sA1 = __builtin_amdgcn_mfma_f32_16x16x32_bf16(kf3, qA1, sA1, 0, 0, 0);
      }
      __builtin_amdgcn_s_setprio(0);
      float btB0 = (kt0 <= qtB) ? btL[kt0 - qtB + 47] : -1e30f;
      float btB1 = (kt0 + 1 <= qtB) ? btL[kt0 + 1 - qtB + 47] : -1e30f;
      b16x8 pfB = exp_pack(sB0, sB1, btB0, btB1, psB);
      __builtin_amdgcn_s_setprio(1);
      oB[0] = __builtin_amdgcn_mfma_f32_16x16x32_bf16(pfB, vf0, oB[0], 0, 0, 0);
      oB[1] = __builtin_amdgcn_mfma_f32_16x16x32_bf16(pfB, vf1, oB[1], 0, 0, 0);
      oB[2] = __builtin_amdgcn_mfma_f32_16x16x32_bf16(pfB, vf2, oB[2], 0, 0, 0);
      oB[3] = __builtin_amdgcn_mfma_f32_16x16x32_bf16(pfB, vf3, oB[3], 0, 0, 0);
      __builtin_amdgcn_s_setprio(0);
      if (doA) {
        float btA0 = (kt0 <= qtA) ? btL[kt0 - qtA + 47] : -1e30f;
        float btA1 = (kt0 + 1 <= qtA) ? btL[kt0 + 1 - qtA + 47] : -1e30f;
        b16x8 pfA = exp_pack(sA0, sA1, btA0, btA1, psA);
        __builtin_amdgcn_s_setprio(1);
        oA[0] = __builtin_amdgcn_mfma_f32_16x16x32_bf16(pfA, vf0, oA[0], 0, 0, 0);
        oA[1] = __builtin_amdgcn_mfma_f32_16x16x32_bf16(pfA, vf1, oA[1], 0, 0, 0);
        oA[2] = __builtin_amdgcn_mfma_f32_16x16x32_bf16(pfA, vf2, oA[2], 0, 0, 0);
        oA[3] = __builtin_amdgcn_mfma_f32_16x16x32_bf16(pfA, vf3, oA[3], 0, 0, 0);
        __builtin_amdgcn_s_setprio(0);
      }
    }

    if (more) WRITE(buf ^ 1);                // vmcnt wait lands HERE (after compute)
    __syncthreads();                         // writes visible; all reads of buf done
    buf ^= 1;
  }

  // denom: per-lane partial (q = n16, keys split across quads) -> full sum
  psA += __shfl_xor(psA, 16); psA += __shfl_xor(psA, 32);
  psB += __shfl_xor(psB, 16); psB += __shfl_xor(psB, 32);
  float invA = 1.0f / psA, invB = 1.0f / psB;
  float pnA[4], pnB[4];
  #pragma unroll
  for (int r = 0; r < 4; ++r) {
    pnA[r] = __shfl(invA, quad * 4 + r);
    pnB[r] = __shfl(invB, quad * 4 + r);
  }

  #pragma unroll
  for (int nt = 0; nt < 4; ++nt) {
    int c = h * 64 + nt * 16 + n16;
    #pragma unroll
    for (int r = 0; r < 4; ++r) {
      int qn = quad * 4 + r;
      yatt[((size_t)b * 768 + qn * 48 + qtA) * 512 + c] = f2b(oA[nt][r] * pnA[r]);
      yatt[((size_t)b * 768 + qn * 48 + qtB) * 512 + c] = f2b(oB[nt][r] * pnB[r]);
    }
  }
}

// ---------------------------------------------------------------------------
// proj (R11 config — best measured): yatt(12288x512,bf16) @ WoT -> out fp32,
// global_load_lds double-buffered staging, 128x128 tiles, grid 96x4.
// ---------------------------------------------------------------------------
__global__ __launch_bounds__(256) void proj_kernel(
    const short* __restrict__ yatt, const short* __restrict__ WT,
    float* __restrict__ out)
{
  __shared__ __align__(16) short smem[16384];  // 32KB double buffer
  int tid = threadIdx.x;
  int w = tid >> 6, lane = tid & 63, n16 = lane & 15, quad = lane >> 4;
  int row0 = blockIdx.x * 128;
  int ncol0 = blockIdx.y * 128;
  const short* Wt = WT + (size_t)3 * 262144;

  f32x4 zero4 = {0.f, 0.f, 0.f, 0.f};
  f32x4 acc[4][4];
  #pragma unroll
  for (int mt = 0; mt < 4; ++mt)
    #pragma unroll
    for (int nt = 0; nt < 4; ++nt) acc[mt][nt] = zero4;

  const short* gA[2];
  const short* gB[2];
  #pragma unroll
  for (int i = 0; i < 2; ++i) {
    int r16 = w + 4 * i;
    gA[i] = yatt + (size_t)(row0 + r16 * 16 + (lane >> 2)) * 512 + (lane & 3) * 8;
    gB[i] = Wt + (size_t)(ncol0 + r16 * 16 + (lane >> 2)) * 512 + (lane & 3) * 8;
  }
  int ldsoff = w * 512 + lane * 8;

  auto stage = [&](int buf, int kt) {
    short* As = smem + buf * 8192;
    short* Bs = As + 4096;
    #pragma unroll
    for (int i = 0; i < 2; ++i) {
      gload16(gA[i] + kt * 32, As + i * 2048 + ldsoff);
      gload16(gB[i] + kt * 32, Bs + i * 2048 + ldsoff);
    }
  };

  int wm = (w >> 1) * 64, wn = (w & 1) * 64;
  stage(0, 0);
  __syncthreads();
  int buf = 0;
  for (int kt = 0; kt < 16; ++kt) {
    if (kt < 15) stage(buf ^ 1, kt + 1);
    const short (*As)[32] = (const short(*)[32])(smem + buf * 8192);
    const short (*Bs)[32] = (const short(*)[32])(smem + buf * 8192 + 4096);
    b16x8 af[4], bf[4];
    #pragma unroll
    for (int mt = 0; mt < 4; ++mt) af[mt] = *(const b16x8*)&As[wm + mt * 16 + n16][quad * 8];
    #pragma unroll
    for (int nt = 0; nt < 4; ++nt) bf[nt] = *(const b16x8*)&Bs[wn + nt * 16 + n16][quad * 8];
    #pragma unroll
    for (int mt = 0; mt < 4; ++mt)
      #pragma unroll
      for (int nt = 0; nt < 4; ++nt)
        acc[mt][nt] = __builtin_amdgcn_mfma_f32_16x16x32_bf16(af[mt], bf[nt], acc[mt][nt], 0, 0, 0);
    __syncthreads();
    buf ^= 1;
  }

  #pragma unroll
  for (int mt = 0; mt < 4; ++mt) {
    int rowb = row0 + wm + mt * 16 + quad * 4;
    #pragma unroll
    for (int nt = 0; nt < 4; ++nt) {
      int colg = ncol0 + wn + nt * 16 + n16;
      #pragma unroll
      for (int r = 0; r < 4; ++r)
        out[(size_t)(rowb + r) * 512 + colg] = acc[mt][nt][r];
    }
  }
}

// ---------------------------------------------------------------------------
extern "C" void kernel_launch(void* const* d_in, const int* in_sizes, int n_in,
                              void* d_out, int out_size, void* d_ws, size_t ws_size,
                              hipStream_t stream) {
  const float* x    = (const float*)d_in[0];
  const float* Wq   = (const float*)d_in[1];
  const float* Wk   = (const float*)d_in[2];
  const float* Wv   = (const float*)d_in[3];
  const float* Wo   = (const float*)d_in[4];
  const float* relT = (const float*)d_in[5];
  const float* relP = (const float*)d_in[6];

  char* wsb = (char*)d_ws;
  const size_t SZ = (size_t)BL_ * C_ * 2;
  short* xb  = (short*)(wsb);
  short* WT  = (short*)(wsb + SZ);
  short* qb  = (short*)(wsb + SZ + 2097152);
  short* kb  = (short*)(wsb + 2 * SZ + 2097152);
  short* vTb = (short*)(wsb + 3 * SZ + 2097152);
  short* yat = (short*)(wsb + 4 * SZ + 2097152 + 4096);

  prep_kernel<<<dim3(4096), dim3(256), 0, stream>>>(x, Wq, Wk, Wv, Wo, xb, WT);
  qkv_kernel<<<dim3(96, 12), dim3(256), 0, stream>>>(xb, WT, qb, kb, vTb);
  attn_kernel<<<dim3(768), dim3(256), 0, stream>>>(qb, kb, vTb, relT, relP, yat);
  proj_kernel<<<dim3(96, 4), dim3(256), 0, stream>>>(yat, WT, (float*)d_out);
}